// Round 2
// baseline (832.696 us; speedup 1.0000x reference)
//
#include <hip/hip_runtime.h>
#include <hip/hip_bf16.h>

typedef __attribute__((ext_vector_type(8))) short short8;
typedef __attribute__((ext_vector_type(4))) float f32x4;

#define HID     512
#define OUTD    256
#define ROWS    32
#define THREADS 512
#define NKT     16

#define WAITV(N) asm volatile("s_waitcnt vmcnt(" #N ")" ::: "memory")
#define WAITL0() asm volatile("s_waitcnt lgkmcnt(0)" ::: "memory")

static __device__ __forceinline__ unsigned short f2bf(float x) {
    __hip_bfloat16 h = __float2bfloat16(x);
    return __builtin_bit_cast(unsigned short, h);
}
static __device__ __forceinline__ unsigned pk2(float a, float b) {
    return (unsigned)f2bf(a) | ((unsigned)f2bf(b) << 16);
}
static __device__ __forceinline__ float bflo(unsigned u) {
    unsigned v = u << 16; return __builtin_bit_cast(float, v);
}
static __device__ __forceinline__ float bfhi(unsigned u) {
    unsigned v = u & 0xffff0000u; return __builtin_bit_cast(float, v);
}
static __device__ __forceinline__ float fast_tanh(float x) {
    float e = __builtin_amdgcn_exp2f(x * 2.885390081777927f);
    float r = __builtin_amdgcn_rcpf(e + 1.0f);
    return fmaf(-2.0f, r, 1.0f);
}

// async global -> LDS, 16B per lane (wave-uniform LDS base + lane*16 implicit)
static __device__ __forceinline__ void gl_lds16(const unsigned short* g, unsigned short* l) {
    __builtin_amdgcn_global_load_lds(
        (const __attribute__((address_space(1))) unsigned int*)g,
        (__attribute__((address_space(3))) unsigned int*)l, 16, 0, 0);
}

// Repack row-major [N][512] f32 -> bf16 fragment chunks: layout [kt][ntg][lane][8e]
// frag f = (kt*NTG + ntg)*64 + lane holds M[ntg*16 + (lane&15)][kt*32 + (lane>>4)*8 + e]
__global__ __launch_bounds__(256) void pack_weights(
    const float* __restrict__ wh, const float* __restrict__ wx,
    const float* __restrict__ hd,
    unsigned short* __restrict__ whp, unsigned short* __restrict__ wxp,
    unsigned short* __restrict__ hdp)
{
    int gid = blockIdx.x * 256 + threadIdx.x;          // [0, 81920)
    const float* src; unsigned short* dst; int f, lane, kt, ntg;
    if (gid < 32768)      { f = gid;         lane = f & 63; ntg = (f >> 6) & 31; kt = f >> 11; src = wh; dst = whp; }
    else if (gid < 65536) { f = gid - 32768; lane = f & 63; ntg = (f >> 6) & 31; kt = f >> 11; src = wx; dst = wxp; }
    else                  { f = gid - 65536; lane = f & 63; ntg = (f >> 6) & 15; kt = f >> 10; src = hd; dst = hdp; }
    int n = ntg * 16 + (lane & 15);
    int k = kt * 32 + (lane >> 4) * 8;
    const float* sp = src + (size_t)n * HID + k;
    float4 a = *(const float4*)sp;
    float4 b = *(const float4*)(sp + 4);
    uint4 o;
    o.x = pk2(a.x, a.y); o.y = pk2(a.z, a.w);
    o.z = pk2(b.x, b.y); o.w = pk2(b.z, b.w);
    *(uint4*)(dst + (size_t)f * 8) = o;
}

// K-loop over 16 chunks from the LDS ring; per-wave private slices, no barriers.
// Invariant: 12 staging issues outstanding at entry; each kt waits vmcnt(8),
// consumes its chunk, re-stages the same slot for chunk+3.
template<int PHASE, bool XPROJ>
static __device__ __forceinline__ void ring_gemm(
    const unsigned short* sfr, unsigned short* ring,
    const unsigned short* __restrict__ whp2, const unsigned short* __restrict__ wxp2,
    f32x4 (&acc)[2][4], const int w, const int l)
{
    const int wo = w * 2048 + l * 8;   // per-thread offset within a chunk (shorts)
    const int ro = w * 2048;           // per-wave base within a slot (shorts)
    #pragma unroll
    for (int kt = 0; kt < NKT; ++kt) {
        const int slot = (PHASE + kt) % 3;
        const int ktn  = (kt + 3) & 15;
        const unsigned short* gsrc = (XPROJ && kt < 13) ? wxp2 : whp2;
        WAITV(8);
        short8 a0 = *(const short8*)(sfr + (kt * 64 + l) * 8);
        short8 a1 = *(const short8*)(sfr + ((NKT + kt) * 64 + l) * 8);
        short8 b0 = *(const short8*)(ring + slot * 16384 + ro + 0 * 512 + l * 8);
        short8 b1 = *(const short8*)(ring + slot * 16384 + ro + 1 * 512 + l * 8);
        short8 b2 = *(const short8*)(ring + slot * 16384 + ro + 2 * 512 + l * 8);
        short8 b3 = *(const short8*)(ring + slot * 16384 + ro + 3 * 512 + l * 8);
        WAITL0();   // ds_reads of this slot complete before DMA re-stage overwrites it
        #pragma unroll
        for (int i = 0; i < 4; ++i)
            gl_lds16(gsrc + ktn * 16384 + wo + i * 512,
                     ring + slot * 16384 + ro + i * 512);
        acc[0][0] = __builtin_amdgcn_mfma_f32_16x16x32_bf16(a0, b0, acc[0][0], 0, 0, 0);
        acc[1][0] = __builtin_amdgcn_mfma_f32_16x16x32_bf16(a1, b0, acc[1][0], 0, 0, 0);
        acc[0][1] = __builtin_amdgcn_mfma_f32_16x16x32_bf16(a0, b1, acc[0][1], 0, 0, 0);
        acc[1][1] = __builtin_amdgcn_mfma_f32_16x16x32_bf16(a1, b1, acc[1][1], 0, 0, 0);
        acc[0][2] = __builtin_amdgcn_mfma_f32_16x16x32_bf16(a0, b2, acc[0][2], 0, 0, 0);
        acc[1][2] = __builtin_amdgcn_mfma_f32_16x16x32_bf16(a1, b2, acc[1][2], 0, 0, 0);
        acc[0][3] = __builtin_amdgcn_mfma_f32_16x16x32_bf16(a0, b3, acc[0][3], 0, 0, 0);
        acc[1][3] = __builtin_amdgcn_mfma_f32_16x16x32_bf16(a1, b3, acc[1][3], 0, 0, 0);
    }
}

static __device__ __forceinline__ void scatter_s(const float (&s)[2][4][4],
    unsigned short* sfrag, const int tIdx)
{
    #pragma unroll
    for (int mt = 0; mt < 2; ++mt)
        #pragma unroll
        for (int nt = 0; nt < 4; ++nt)
            #pragma unroll
            for (int i = 0; i < 4; ++i) {
                const int off = (mt * 16384 + (nt >> 1) * 1024 + ((2 * nt) & 3) * 256 + i * 16) >> 1;
                sfrag[tIdx + off] = f2bf(s[mt][nt][i]);
            }
}

template<int PHASE>
static __device__ __forceinline__ void do_step(
    float (&s)[2][4][4], unsigned (&hh)[3][2][4][2], const float (&xp)[2][4][4],
    unsigned short* sfrag, unsigned short* ring, const unsigned short* __restrict__ whp2,
    const int w, const int l, const int tIdx,
    const float g1, const float g2, const float g3)
{
    scatter_s(s, sfrag, tIdx);
    WAITL0(); __builtin_amdgcn_s_barrier();     // raw barrier: no vmcnt drain

    f32x4 acc[2][4];
    #pragma unroll
    for (int mt = 0; mt < 2; ++mt)
        #pragma unroll
        for (int nt = 0; nt < 4; ++nt)
            acc[mt][nt] = (f32x4){0.f, 0.f, 0.f, 0.f};
    ring_gemm<PHASE, false>(sfrag, ring, whp2, nullptr, acc, w, l);
    WAITL0(); __builtin_amdgcn_s_barrier();     // all sfrag reads done before next scatter

    #pragma unroll
    for (int mt = 0; mt < 2; ++mt)
        #pragma unroll
        for (int nt = 0; nt < 4; ++nt)
            #pragma unroll
            for (int p = 0; p < 2; ++p) {
                unsigned u1 = hh[0][mt][nt][p];
                unsigned u2 = hh[1][mt][nt][p];
                unsigned u3 = hh[2][mt][nt][p];
                float so0, so1;
                {
                    const int i = p * 2;
                    float pre = acc[mt][nt][i] + xp[mt][nt][i]
                              + g1 * bflo(u1) + g2 * bflo(u2) + g3 * bflo(u3);
                    float hn = fast_tanh(pre);
                    so0 = s[mt][nt][i];
                    s[mt][nt][i] = 0.5f * so0 + 0.5f * hn;
                }
                {
                    const int i = p * 2 + 1;
                    float pre = acc[mt][nt][i] + xp[mt][nt][i]
                              + g1 * bfhi(u1) + g2 * bfhi(u2) + g3 * bfhi(u3);
                    float hn = fast_tanh(pre);
                    so1 = s[mt][nt][i];
                    s[mt][nt][i] = 0.5f * so1 + 0.5f * hn;
                }
                hh[2][mt][nt][p] = u2;
                hh[1][mt][nt][p] = u1;
                hh[0][mt][nt][p] = pk2(so0, so1);
            }
}

__global__ __launch_bounds__(THREADS, 2) void toroidal(
    const float* __restrict__ x,
    const unsigned short* __restrict__ wxp2,
    const unsigned short* __restrict__ whp2,
    const unsigned short* __restrict__ hdp2,
    const float* __restrict__ wxb, const float* __restrict__ whb,
    const float* __restrict__ hdb,
    const float* __restrict__ gamma_p, const float* __restrict__ alphas,
    const int* __restrict__ steps_p,
    float* __restrict__ out)
{
    __shared__ __align__(16) unsigned short sfrag[ROWS * HID];   // 32 KiB, A-frag packed
    __shared__ __align__(16) unsigned short ring[3 * 16384];     // 96 KiB staging ring

    const int tid = threadIdx.x;
    const int w = tid >> 6;
    const int l = tid & 63;
    const int q = l >> 4;
    const int c = l & 15;
    const int rbase = blockIdx.x * ROWS;
    const int ro = w * 2048;

    // ---- all scalar/bias global loads BEFORE the vmcnt baseline reset ----
    const float g  = gamma_p[0];
    const float g1 = g * alphas[0], g2 = g * alphas[1], g3 = g * alphas[2];
    const int nsteps = steps_p[0];
    float bsum[4];
    #pragma unroll
    for (int nt = 0; nt < 4; ++nt) {
        int col = w * 64 + nt * 16 + c;
        bsum[nt] = wxb[col] + whb[col];
    }
    float hb[2];
    #pragma unroll
    for (int nt = 0; nt < 2; ++nt) hb[nt] = hdb[w * 32 + nt * 16 + c];

    // ---- pack x tile (32 rows) into sfrag as bf16 A-fragments ----
    #pragma unroll
    for (int j = 0; j < 4; ++j) {
        int f = tid + j * THREADS;                 // [0, 2048)
        int mt = f >> 10;
        int kt = (f >> 6) & 15;
        int lf = f & 63;
        int row = mt * 16 + (lf & 15);
        int k0  = kt * 32 + (lf >> 4) * 8;
        const float* sp = x + (size_t)(rbase + row) * HID + k0;
        float4 a = *(const float4*)sp;
        float4 b = *(const float4*)(sp + 4);
        uint4 o;
        o.x = pk2(a.x, a.y); o.y = pk2(a.z, a.w);
        o.z = pk2(b.x, b.y); o.w = pk2(b.z, b.w);
        *(uint4*)(sfrag + (size_t)f * 8) = o;
    }
    __syncthreads();    // safe: before any staging

    WAITV(0);           // vmcnt baseline = 0 for counted ring waits
    {   // prologue: stage wxp2 chunks 0..2
        const int wo = ro + l * 8;
        #pragma unroll
        for (int cch = 0; cch < 3; ++cch)
            #pragma unroll
            for (int i = 0; i < 4; ++i)
                gl_lds16(wxp2 + cch * 16384 + wo + i * 512,
                         ring + cch * 16384 + ro + i * 512);
    }

    // ---- xproj via ring (chunks 0..15; stages whp2 chunks 0..2 at the tail) ----
    f32x4 acc[2][4];
    #pragma unroll
    for (int mt = 0; mt < 2; ++mt)
        #pragma unroll
        for (int nt = 0; nt < 4; ++nt)
            acc[mt][nt] = (f32x4){0.f, 0.f, 0.f, 0.f};
    ring_gemm<0, true>(sfrag, ring, whp2, wxp2, acc, w, l);

    float xp[2][4][4];
    #pragma unroll
    for (int nt = 0; nt < 4; ++nt)
        #pragma unroll
        for (int mt = 0; mt < 2; ++mt)
            #pragma unroll
            for (int i = 0; i < 4; ++i)
                xp[mt][nt][i] = acc[mt][nt][i] + bsum[nt];

    WAITL0(); __builtin_amdgcn_s_barrier();   // xproj sfrag reads done before step scatter

    float s[2][4][4];
    unsigned hh[3][2][4][2];
    #pragma unroll
    for (int mt = 0; mt < 2; ++mt)
        #pragma unroll
        for (int nt = 0; nt < 4; ++nt)
            #pragma unroll
            for (int i = 0; i < 4; ++i) s[mt][nt][i] = 0.f;
    #pragma unroll
    for (int a = 0; a < 3; ++a)
        #pragma unroll
        for (int mt = 0; mt < 2; ++mt)
            #pragma unroll
            for (int nt = 0; nt < 4; ++nt)
                #pragma unroll
                for (int p = 0; p < 2; ++p) hh[a][mt][nt][p] = 0u;

    const int tIdx = (w * 2048 + q * 64 + (l & 7) * 2 + (((l >> 3) & 1) << 8)) >> 1;

    // step i uses chunks 16+16i+kt -> slot phase (1+i)%3: pattern 1,2,0 repeating
    int t = 0;
    while (t + 3 <= nsteps) {
        do_step<1>(s, hh, xp, sfrag, ring, whp2, w, l, tIdx, g1, g2, g3);
        do_step<2>(s, hh, xp, sfrag, ring, whp2, w, l, tIdx, g1, g2, g3);
        do_step<0>(s, hh, xp, sfrag, ring, whp2, w, l, tIdx, g1, g2, g3);
        t += 3;
    }
    if (t < nsteps) { do_step<1>(s, hh, xp, sfrag, ring, whp2, w, l, tIdx, g1, g2, g3); ++t; }
    if (t < nsteps) { do_step<2>(s, hh, xp, sfrag, ring, whp2, w, l, tIdx, g1, g2, g3); ++t; }

    // ---- head: out = s_final @ Head^T + Head_b, via fresh counted ring ----
    scatter_s(s, sfrag, tIdx);
    WAITL0(); __builtin_amdgcn_s_barrier();
    WAITV(0);           // drain leftover (wasted) step stages; reset baseline

    #pragma unroll
    for (int j = 0; j < 3; ++j)
        #pragma unroll
        for (int i = 0; i < 4; ++i)
            gl_lds16(hdp2 + (size_t)(((2 * j + (i >> 1)) * 16 + 2 * w + (i & 1)) * 512 + l * 8),
                     ring + (j % 3) * 16384 + ro + i * 512);

    f32x4 acch[2][2];
    #pragma unroll
    for (int mt = 0; mt < 2; ++mt)
        #pragma unroll
        for (int nt = 0; nt < 2; ++nt)
            acch[mt][nt] = (f32x4){0.f, 0.f, 0.f, 0.f};

    #pragma unroll
    for (int j = 0; j < 8; ++j) {
        const int slot = j % 3;
        if (j <= 5)      { WAITV(8); }
        else if (j == 6) { WAITV(4); }
        else             { WAITV(0); }
        short8 a00 = *(const short8*)(sfrag + ((2 * j)          * 64 + l) * 8);
        short8 a01 = *(const short8*)(sfrag + ((2 * j + 1)      * 64 + l) * 8);
        short8 a10 = *(const short8*)(sfrag + ((16 + 2 * j)     * 64 + l) * 8);
        short8 a11 = *(const short8*)(sfrag + ((16 + 2 * j + 1) * 64 + l) * 8);
        short8 b00 = *(const short8*)(ring + slot * 16384 + ro + 0 * 512 + l * 8);
        short8 b01 = *(const short8*)(ring + slot * 16384 + ro + 1 * 512 + l * 8);
        short8 b10 = *(const short8*)(ring + slot * 16384 + ro + 2 * 512 + l * 8);
        short8 b11 = *(const short8*)(ring + slot * 16384 + ro + 3 * 512 + l * 8);
        WAITL0();
        if (j + 3 < 8) {
            const int jn = j + 3, sn = (j + 3) % 3;
            #pragma unroll
            for (int i = 0; i < 4; ++i)
                gl_lds16(hdp2 + (size_t)(((2 * jn + (i >> 1)) * 16 + 2 * w + (i & 1)) * 512 + l * 8),
                         ring + sn * 16384 + ro + i * 512);
        }
        acch[0][0] = __builtin_amdgcn_mfma_f32_16x16x32_bf16(a00, b00, acch[0][0], 0, 0, 0);
        acch[1][0] = __builtin_amdgcn_mfma_f32_16x16x32_bf16(a10, b00, acch[1][0], 0, 0, 0);
        acch[0][1] = __builtin_amdgcn_mfma_f32_16x16x32_bf16(a00, b01, acch[0][1], 0, 0, 0);
        acch[1][1] = __builtin_amdgcn_mfma_f32_16x16x32_bf16(a10, b01, acch[1][1], 0, 0, 0);
        acch[0][0] = __builtin_amdgcn_mfma_f32_16x16x32_bf16(a01, b10, acch[0][0], 0, 0, 0);
        acch[1][0] = __builtin_amdgcn_mfma_f32_16x16x32_bf16(a11, b10, acch[1][0], 0, 0, 0);
        acch[0][1] = __builtin_amdgcn_mfma_f32_16x16x32_bf16(a01, b11, acch[0][1], 0, 0, 0);
        acch[1][1] = __builtin_amdgcn_mfma_f32_16x16x32_bf16(a11, b11, acch[1][1], 0, 0, 0);
    }

    #pragma unroll
    for (int nt = 0; nt < 2; ++nt) {
        int col = w * 32 + nt * 16 + c;
        #pragma unroll
        for (int mt = 0; mt < 2; ++mt)
            #pragma unroll
            for (int i = 0; i < 4; ++i)
                out[(size_t)(rbase + mt * 16 + q * 4 + i) * OUTD + col] = acch[mt][nt][i] + hb[nt];
    }
}

extern "C" void kernel_launch(void* const* d_in, const int* in_sizes, int n_in,
                              void* d_out, int out_size, void* d_ws, size_t ws_size,
                              hipStream_t stream) {
    (void)n_in; (void)out_size;
    const float* x    = (const float*)d_in[0];
    const float* Wx_w = (const float*)d_in[1];
    const float* Wx_b = (const float*)d_in[2];
    const float* Wh_w = (const float*)d_in[3];
    const float* Wh_b = (const float*)d_in[4];
    const float* Hd_w = (const float*)d_in[5];
    const float* Hd_b = (const float*)d_in[6];
    const float* gma  = (const float*)d_in[7];
    const float* alp  = (const float*)d_in[8];
    const int*   stp  = (const int*)d_in[9];
    float* out = (float*)d_out;

    if (ws_size < (size_t)(512 * 512 * 2 * 2 + 256 * 512 * 2)) return;
    unsigned short* whp = (unsigned short*)d_ws;
    unsigned short* wxp = whp + 512 * 512;
    unsigned short* hdp = wxp + 512 * 512;

    pack_weights<<<320, 256, 0, stream>>>(Wh_w, Wx_w, Hd_w, whp, wxp, hdp);

    int batch = in_sizes[0] / HID;                 // 8192
    int nblk  = batch / ROWS;                      // 256
    toroidal<<<nblk, THREADS, 0, stream>>>(x, wxp, whp, hdp, Wx_b, Wh_b, Hd_b,
                                           gma, alp, stp, out);
}